// Round 1
// baseline (523.451 us; speedup 1.0000x reference)
//
#include <hip/hip_runtime.h>
#include <hip/hip_bf16.h>

typedef __hip_bfloat16 bf16;
typedef __attribute__((ext_vector_type(8))) short bf16x8;  // 8 bf16 in 4 VGPRs
typedef __attribute__((ext_vector_type(4))) float f32x4;

#define SEQ_LEN 2048
#define K_MAX   32
#define D_SPEC  256
#define D_MODEL 768
#define N_LAYERS 4
#define BATCH   2
#define MTOT    (BATCH * SEQ_LEN)       // 4096 rows (b*2048+t)
#define NU      (D_SPEC * K_MAX * 2)    // 16384 = (o*32+k)*2+ri
#define NCOND   (2 * D_MODEL)           // 1536

__device__ inline float b2f(bf16 h) { return __bfloat162float(h); }

__device__ inline void gload16(const void* gp, void* lp) {
  __builtin_amdgcn_global_load_lds((const __attribute__((address_space(1))) void*)gp,
                                   (__attribute__((address_space(3))) void*)lp, 16, 0, 0);
}

// ---------------------------------------------------------------------------
// prep: Bmat[n*256+i] = conv_w[o,i,k,ri] with n=(o*32+k)*2+ri  (B^T layout for GEMM)
//       wsb  = bf16(w_shared)   [768][256]   (already B^T: row=dmodel, col=dspec)
//       lwb  = bf16(layer_w)    [4][1536][768] (already B^T per layer)
// ---------------------------------------------------------------------------
__global__ void prep(const bf16* __restrict__ conv_w, const float* __restrict__ w_shared,
                     const float* __restrict__ layer_w,
                     bf16* __restrict__ Bmat, bf16* __restrict__ wsb, bf16* __restrict__ lwb) {
  int idx = blockIdx.x * blockDim.x + threadIdx.x;
  int stride = gridDim.x * blockDim.x;
  for (int j = idx; j < NU * D_SPEC; j += stride) {
    int n = j >> 8, i = j & 255;
    int o = n >> 6, kc = n & 63;                 // kc = k*2+ri
    Bmat[j] = conv_w[o * 16384 + i * 64 + kc];
  }
  for (int j = idx; j < D_MODEL * D_SPEC; j += stride) wsb[j] = __float2bfloat16(w_shared[j]);
  for (int j = idx; j < N_LAYERS * NCOND * D_MODEL; j += stride) lwb[j] = __float2bfloat16(layer_w[j]);
}

// ---------------------------------------------------------------------------
// 128x128-tile bf16 MFMA GEMM (m97 pattern): A[m][K] row-major, B^T[n][K] row-major.
// EPI 0: store bf16 (u) ; EPI 1: +bias, SiLU, store bf16 (hidden) ; EPI 2: +bias[z], store f32 (cond)
// ---------------------------------------------------------------------------
template <int EPI>
__global__ __launch_bounds__(256, 2) void gemm_k(
    const bf16* __restrict__ A, const bf16* __restrict__ B, void* __restrict__ Cp,
    const float* __restrict__ bias, int N, int K,
    long long c_bstride, long long b_bstride, int bias_bstride) {
  __shared__ bf16 As[128 * 32];
  __shared__ bf16 Bs[128 * 32];
  const int tid = threadIdx.x;
  const int wave = tid >> 6, lane = tid & 63;
  const int wm = (wave >> 1) << 6, wn = (wave & 1) << 6;   // 2x2 waves of 64x64
  const int lrow = lane & 15, quad = lane >> 4;
  const int m0 = blockIdx.y << 7, n0 = blockIdx.x << 7;
  const int z = blockIdx.z;
  const bf16* Bz = B + (size_t)z * b_bstride;

  f32x4 acc[4][4] = {};

  for (int k0 = 0; k0 < K; k0 += 32) {
    // stage A-tile and B-tile (128x32 bf16 = 8 KB each) via async direct-to-LDS, 16 B/lane
#pragma unroll
    for (int c = 0; c < 2; ++c) {
      int rr = ((wave * 2 + c) << 4) + (lane >> 2);   // tile row (64 B per row)
      int cb = (lane & 3) << 4;                       // byte within row
      int lq = (((wave * 2 + c) << 6) + lane) << 4;   // LDS byte offset = wave-uniform + lane*16
      gload16((const char*)A  + (((size_t)(m0 + rr) * K + k0) << 1) + cb, (char*)As + lq);
      gload16((const char*)Bz + (((size_t)(n0 + rr) * K + k0) << 1) + cb, (char*)Bs + lq);
    }
    __syncthreads();
    bf16x8 af[4], bfr[4];
#pragma unroll
    for (int i = 0; i < 4; ++i) {
      af[i]  = *(const bf16x8*)(As + ((wm + (i << 4) + lrow) << 5) + (quad << 3));
      bfr[i] = *(const bf16x8*)(Bs + ((wn + (i << 4) + lrow) << 5) + (quad << 3));
    }
#pragma unroll
    for (int mt = 0; mt < 4; ++mt)
#pragma unroll
      for (int nt = 0; nt < 4; ++nt)
        acc[mt][nt] = __builtin_amdgcn_mfma_f32_16x16x32_bf16(af[mt], bfr[nt], acc[mt][nt], 0, 0, 0);
    __syncthreads();
  }

#pragma unroll
  for (int mt = 0; mt < 4; ++mt) {
#pragma unroll
    for (int nt = 0; nt < 4; ++nt) {
#pragma unroll
      for (int r = 0; r < 4; ++r) {
        int gm = m0 + wm + (mt << 4) + (quad << 2) + r;  // C/D: row = quad*4+reg
        int gn = n0 + wn + (nt << 4) + lrow;             //      col = lane&15
        float v = acc[mt][nt][r];
        if (EPI == 0) {
          ((bf16*)Cp)[(size_t)gm * N + gn] = __float2bfloat16(v);
        } else if (EPI == 1) {
          v += bias[gn];
          v = v / (1.f + __expf(-v));                    // SiLU
          ((bf16*)Cp)[(size_t)gm * N + gn] = __float2bfloat16(v);
        } else {
          v += bias[(size_t)z * bias_bstride + gn];
          ((float*)Cp)[(size_t)z * c_bstride + (size_t)gm * N + gn] = v;
        }
      }
    }
  }
}

// ---------------------------------------------------------------------------
// Chunked complex prefix scan over t of a[t] = tw(t,k) * (u + x_self), then modReLU+pool.
// Blocks: (b, chunk of 256 t, group of 8 o) = 2*8*32 = 512. Threads: o_sub(8) x k(32).
// ---------------------------------------------------------------------------
__device__ inline void scan_term(const bf16* __restrict__ u, const bf16* __restrict__ x,
                                 int m, int o, int k, float& ar, float& ai) {
  __hip_bfloat162 uv = *(const __hip_bfloat162*)(u + ((size_t)m << 14) + (((o << 5) + k) << 1));
  float ur = b2f(uv.x), ui = b2f(uv.y);
  float xv = b2f(x[((size_t)m << 8) + o]);
  const float c1 = -6.283185307179586f / 2048.0f;
  float s, c;
  __sincosf(c1 * (float)(((m & 2047) * k) & 2047), &s, &c);  // exact angle reduction mod 2pi
  float urx = ur + xv;
  ar = c * urx - s * ui;
  ai = c * ui + s * urx;
}

__global__ __launch_bounds__(256) void scan1(const bf16* __restrict__ u, const bf16* __restrict__ x,
                                             float* __restrict__ totals) {
  const int bId = blockIdx.x;
  const int ogrp = bId & 31, chunk = (bId >> 5) & 7, b = bId >> 8;
  const int tid = threadIdx.x, o_sub = tid >> 5, k = tid & 31;
  const int o = (ogrp << 3) + o_sub;
  float sr = 0.f, si = 0.f;
  const int t0 = chunk << 8;
  for (int tt = 0; tt < 256; ++tt) {
    int m = (b << 11) + t0 + tt;
    float ar, ai;
    scan_term(u, x, m, o, k, ar, ai);
    sr += ar; si += ai;
  }
  size_t tb = (((size_t)((b * 8 + chunk) * 256 + o)) * 32 + k) * 2;
  totals[tb] = sr; totals[tb + 1] = si;
}

__global__ __launch_bounds__(256) void scan2(const bf16* __restrict__ u, const bf16* __restrict__ x,
                                             const float* __restrict__ totals,
                                             const bf16* __restrict__ mrb, bf16* __restrict__ pooled) {
  const int bId = blockIdx.x;
  const int ogrp = bId & 31, chunk = (bId >> 5) & 7, b = bId >> 8;
  const int tid = threadIdx.x, o_sub = tid >> 5, k = tid & 31;
  const int o = (ogrp << 3) + o_sub;
  float sr = 0.f, si = 0.f;
  for (int cc = 0; cc < chunk; ++cc) {  // prefix offset from earlier chunks
    size_t tb = (((size_t)((b * 8 + cc) * 256 + o)) * 32 + k) * 2;
    sr += totals[tb]; si += totals[tb + 1];
  }
  const float biaso = b2f(mrb[o]);
  const float norm = 0.022097086912079608f;  // 1/sqrt(2048)
  const int t0 = chunk << 8;
  for (int tt = 0; tt < 256; ++tt) {
    int m = (b << 11) + t0 + tt;
    float ar, ai;
    scan_term(u, x, m, o, k, ar, ai);
    sr += ar; si += ai;
    float r = norm * sr, im = norm * si;
    float h2 = r * r + im * im;
    float he = sqrtf(h2 + 1e-8f);
    float nm = fmaxf(he - biaso, 0.f);
    float inv = h2 > 0.f ? rsqrtf(h2) : 0.f;       // cos/sin of atan2 without atan2
    float zr = h2 > 0.f ? nm * r * inv : nm;       // atan2(0,0)=0 -> cos=1
    float zi = nm * im * inv;
    float m2 = sqrtf(zr * zr + zi * zi + 1e-8f);
#pragma unroll
    for (int mm = 1; mm < 32; mm <<= 1) m2 += __shfl_xor(m2, mm, 64);  // reduce over k
    if (k == 0) pooled[((size_t)m << 8) + o] = __float2bfloat16(m2 * (1.f / 32.f));
  }
}

// ---------------------------------------------------------------------------
extern "C" void kernel_launch(void* const* d_in, const int* in_sizes, int n_in,
                              void* d_out, int out_size, void* d_ws, size_t ws_size,
                              hipStream_t stream) {
  const bf16* x        = (const bf16*)d_in[0];
  const bf16* conv_w   = (const bf16*)d_in[1];
  const bf16* mrb      = (const bf16*)d_in[2];
  const float* w_shared = (const float*)d_in[3];
  const float* b_shared = (const float*)d_in[4];
  const float* layer_w  = (const float*)d_in[5];
  const float* layer_b  = (const float*)d_in[6];
  float* out = (float*)d_out;

  char* ws = (char*)d_ws;
  bf16* Bmat   = (bf16*)(ws);                 // 16384*256*2   =   8,388,608
  bf16* u      = (bf16*)(ws + 8388608);       // 4096*16384*2  = 134,217,728
  float* totals = (float*)(ws + 142606336);   // 131072*2*4    =   1,048,576
  bf16* pooled = (bf16*)(ws + 143654912);     // 4096*256*2    =   2,097,152
  bf16* wsb    = (bf16*)(ws + 145752064);     // 768*256*2     =     393,216
  bf16* hidden = (bf16*)(ws + 146145280);     // 4096*768*2    =   6,291,456
  bf16* lwb    = (bf16*)(ws + 152436736);     // 4*1536*768*2  =   9,437,184  (end ~161.9 MB)

  prep<<<2048, 256, 0, stream>>>(conv_w, w_shared, layer_w, Bmat, wsb, lwb);

  // u[m][(o*32+k)*2+ri] = sum_i x[m][i] * conv_w[o,i,k,ri]
  gemm_k<0><<<dim3(NU / 128, MTOT / 128, 1), 256, 0, stream>>>(
      x, Bmat, u, nullptr, NU, D_SPEC, 0, 0, 0);

  scan1<<<512, 256, 0, stream>>>(u, x, totals);
  scan2<<<512, 256, 0, stream>>>(u, x, totals, mrb, pooled);

  // hidden = silu(pooled @ w_shared^T + b_shared)
  gemm_k<1><<<dim3(D_MODEL / 128, MTOT / 128, 1), 256, 0, stream>>>(
      pooled, wsb, hidden, b_shared, D_MODEL, D_SPEC, 0, 0, 0);

  // cond[l] = hidden @ layer_w[l]^T + layer_b[l]
  gemm_k<2><<<dim3(NCOND / 128, MTOT / 128, N_LAYERS), 256, 0, stream>>>(
      hidden, lwb, out, layer_b, NCOND, D_MODEL,
      (long long)MTOT * NCOND, (long long)NCOND * D_MODEL, NCOND);
}

// Round 2
// 381.256 us; speedup vs baseline: 1.3730x; 1.3730x over previous
//
#include <hip/hip_runtime.h>
#include <hip/hip_bf16.h>

typedef __hip_bfloat16 bf16;
typedef __attribute__((ext_vector_type(8))) short bf16x8;  // 8 bf16 in 4 VGPRs
typedef __attribute__((ext_vector_type(4))) float f32x4;

#define SEQ_LEN 2048
#define K_MAX   32
#define D_SPEC  256
#define D_MODEL 768
#define N_LAYERS 4
#define BATCH   2
#define MTOT    (BATCH * SEQ_LEN)       // 4096 rows (b*2048+t)
#define NU      (D_SPEC * K_MAX * 2)    // 16384 = (o*32+k)*2+ri
#define NCOND   (2 * D_MODEL)           // 1536
#define NCHUNK  32
#define CLEN    64                      // SEQ_LEN / NCHUNK

__device__ inline float b2f(bf16 h) { return __bfloat162float(h); }

__device__ inline void gload16(const void* gp, void* lp) {
  __builtin_amdgcn_global_load_lds((const __attribute__((address_space(1))) void*)gp,
                                   (__attribute__((address_space(3))) void*)lp, 16, 0, 0);
}

// Full-rate DPP reduction over each 32-lane half; result valid in lanes 31 / 63.
// old=0 AND bound_ctrl=1 so OOB lanes contribute 0 under either convention.
__device__ inline float row_reduce32(float v) {
  v += __int_as_float(__builtin_amdgcn_update_dpp(0, __float_as_int(v), 0x111, 0xF, 0xF, true)); // row_shr:1
  v += __int_as_float(__builtin_amdgcn_update_dpp(0, __float_as_int(v), 0x112, 0xF, 0xF, true)); // row_shr:2
  v += __int_as_float(__builtin_amdgcn_update_dpp(0, __float_as_int(v), 0x114, 0xF, 0xF, true)); // row_shr:4
  v += __int_as_float(__builtin_amdgcn_update_dpp(0, __float_as_int(v), 0x118, 0xF, 0xF, true)); // row_shr:8
  v += __int_as_float(__builtin_amdgcn_update_dpp(0, __float_as_int(v), 0x142, 0xF, 0xF, true)); // row_bcast:15
  return v;
}

// ---------------------------------------------------------------------------
// prep: Bmat[n*256+i] = conv_w[o,i,k,ri] with n=(o*32+k)*2+ri  (B^T layout for GEMM)
//       wsb = bf16(w_shared) [768][256] ; lwb = bf16(layer_w) [4][1536][768]
// ---------------------------------------------------------------------------
__global__ void prep(const bf16* __restrict__ conv_w, const float* __restrict__ w_shared,
                     const float* __restrict__ layer_w,
                     bf16* __restrict__ Bmat, bf16* __restrict__ wsb, bf16* __restrict__ lwb) {
  int idx = blockIdx.x * blockDim.x + threadIdx.x;
  int stride = gridDim.x * blockDim.x;
  for (int j = idx; j < NU * D_SPEC; j += stride) {
    int n = j >> 8, i = j & 255;
    int o = n >> 6, kc = n & 63;                 // kc = k*2+ri
    Bmat[j] = conv_w[o * 16384 + i * 64 + kc];
  }
  for (int j = idx; j < D_MODEL * D_SPEC; j += stride) wsb[j] = __float2bfloat16(w_shared[j]);
  for (int j = idx; j < N_LAYERS * NCOND * D_MODEL; j += stride) lwb[j] = __float2bfloat16(layer_w[j]);
}

// ---------------------------------------------------------------------------
// 128x128-tile bf16 MFMA GEMM (m97 pattern): A[m][K] row-major, B^T[n][K] row-major.
// EPI 0: store bf16 (u) ; EPI 1: +bias, SiLU, store bf16 (hidden) ; EPI 2: +bias[z], store f32 (cond)
// ---------------------------------------------------------------------------
template <int EPI>
__global__ __launch_bounds__(256, 2) void gemm_k(
    const bf16* __restrict__ A, const bf16* __restrict__ B, void* __restrict__ Cp,
    const float* __restrict__ bias, int N, int K,
    long long c_bstride, long long b_bstride, int bias_bstride) {
  __shared__ bf16 As[128 * 32];
  __shared__ bf16 Bs[128 * 32];
  const int tid = threadIdx.x;
  const int wave = tid >> 6, lane = tid & 63;
  const int wm = (wave >> 1) << 6, wn = (wave & 1) << 6;   // 2x2 waves of 64x64
  const int lrow = lane & 15, quad = lane >> 4;
  const int m0 = blockIdx.y << 7, n0 = blockIdx.x << 7;
  const int z = blockIdx.z;
  const bf16* Bz = B + (size_t)z * b_bstride;

  f32x4 acc[4][4] = {};

  for (int k0 = 0; k0 < K; k0 += 32) {
#pragma unroll
    for (int c = 0; c < 2; ++c) {
      int rr = ((wave * 2 + c) << 4) + (lane >> 2);   // tile row (64 B per row)
      int cb = (lane & 3) << 4;                       // byte within row
      int lq = (((wave * 2 + c) << 6) + lane) << 4;   // LDS byte offset = wave-uniform + lane*16
      gload16((const char*)A  + (((size_t)(m0 + rr) * K + k0) << 1) + cb, (char*)As + lq);
      gload16((const char*)Bz + (((size_t)(n0 + rr) * K + k0) << 1) + cb, (char*)Bs + lq);
    }
    __syncthreads();
    bf16x8 af[4], bfr[4];
#pragma unroll
    for (int i = 0; i < 4; ++i) {
      af[i]  = *(const bf16x8*)(As + ((wm + (i << 4) + lrow) << 5) + (quad << 3));
      bfr[i] = *(const bf16x8*)(Bs + ((wn + (i << 4) + lrow) << 5) + (quad << 3));
    }
#pragma unroll
    for (int mt = 0; mt < 4; ++mt)
#pragma unroll
      for (int nt = 0; nt < 4; ++nt)
        acc[mt][nt] = __builtin_amdgcn_mfma_f32_16x16x32_bf16(af[mt], bfr[nt], acc[mt][nt], 0, 0, 0);
    __syncthreads();
  }

#pragma unroll
  for (int mt = 0; mt < 4; ++mt) {
#pragma unroll
    for (int nt = 0; nt < 4; ++nt) {
#pragma unroll
      for (int r = 0; r < 4; ++r) {
        int gm = m0 + wm + (mt << 4) + (quad << 2) + r;  // C/D: row = quad*4+reg
        int gn = n0 + wn + (nt << 4) + lrow;             //      col = lane&15
        float v = acc[mt][nt][r];
        if (EPI == 0) {
          ((bf16*)Cp)[(size_t)gm * N + gn] = __float2bfloat16(v);
        } else if (EPI == 1) {
          v += bias[gn];
          v = v / (1.f + __expf(-v));                    // SiLU
          ((bf16*)Cp)[(size_t)gm * N + gn] = __float2bfloat16(v);
        } else {
          v += bias[(size_t)z * bias_bstride + gn];
          ((float*)Cp)[(size_t)z * c_bstride + (size_t)gm * N + gn] = v;
        }
      }
    }
  }
}

// ---------------------------------------------------------------------------
// Chunked complex prefix scan of a[t] = tw(t,k)*(u + x_self) over t.
// Grid: b(2) x chunk(32) x ogrp(32) = 2048 blocks; threads: o_sub(8) x k(32).
// Twiddle via 4-FMA rotation recurrence (sincos only at init).
// ---------------------------------------------------------------------------
__global__ __launch_bounds__(256) void scan1(const bf16* __restrict__ u, const bf16* __restrict__ x,
                                             float* __restrict__ totals) {
  const int bId = blockIdx.x;
  const int ogrp = bId & 31, chunk = (bId >> 5) & 31, b = bId >> 10;
  const int tid = threadIdx.x, o_sub = tid >> 5, k = tid & 31;
  const int o = (ogrp << 3) + o_sub;
  const int t0 = chunk << 6;
  const float c1 = -6.283185307179586f / 2048.0f;
  float c, s, cd, sd;
  __sincosf(c1 * (float)((t0 * k) & 2047), &s, &c);
  __sincosf(c1 * (float)k, &sd, &cd);
  float sr = 0.f, si = 0.f;
  const bf16* up = u + (((size_t)((b << 11) + t0)) << 14) + (((o << 5) + k) << 1);
  const bf16* xp = x + (((size_t)((b << 11) + t0)) << 8) + o;
#pragma unroll 4
  for (int tt = 0; tt < CLEN; ++tt) {
    __hip_bfloat162 uv = *(const __hip_bfloat162*)up; up += NU;
    float xv = b2f(*xp); xp += D_SPEC;
    float ur = b2f(uv.x) + xv, ui = b2f(uv.y);
    sr += c * ur - s * ui;
    si += c * ui + s * ur;
    float cn = c * cd - s * sd; s = s * cd + c * sd; c = cn;
  }
  size_t tb = ((((size_t)(b * NCHUNK + chunk)) << 13) + (o << 5) + k) << 1;
  totals[tb] = sr; totals[tb + 1] = si;
}

// In-place exclusive prefix over chunks for each of the 16384 chains.
__global__ void tprefix(float* __restrict__ totals) {
  int id = blockIdx.x * blockDim.x + threadIdx.x;   // 16384 = (b*8192)+(o*32+k)
  int b = id >> 13, ok = id & 8191;
  float sr = 0.f, si = 0.f;
  for (int cc = 0; cc < NCHUNK; ++cc) {
    size_t idx = ((((size_t)(b * NCHUNK + cc)) << 13) + ok) << 1;
    float tr = totals[idx], ti = totals[idx + 1];
    totals[idx] = sr; totals[idx + 1] = si;
    sr += tr; si += ti;
  }
}

__global__ __launch_bounds__(256) void scan2(const bf16* __restrict__ u, const bf16* __restrict__ x,
                                             const float* __restrict__ totals,
                                             const bf16* __restrict__ mrb, bf16* __restrict__ pooled) {
  const int bId = blockIdx.x;
  const int ogrp = bId & 31, chunk = (bId >> 5) & 31, b = bId >> 10;
  const int tid = threadIdx.x, o_sub = tid >> 5, k = tid & 31;
  const int o = (ogrp << 3) + o_sub;
  const int t0 = chunk << 6;
  size_t tb = ((((size_t)(b * NCHUNK + chunk)) << 13) + (o << 5) + k) << 1;
  float sr = totals[tb], si = totals[tb + 1];
  const float c1 = -6.283185307179586f / 2048.0f;
  float c, s, cd, sd;
  __sincosf(c1 * (float)((t0 * k) & 2047), &s, &c);
  __sincosf(c1 * (float)k, &sd, &cd);
  const float biaso = b2f(mrb[o]);
  const float norm = 0.022097086912079608f;  // 1/sqrt(2048)
  const bf16* up = u + (((size_t)((b << 11) + t0)) << 14) + (((o << 5) + k) << 1);
  const bf16* xp = x + (((size_t)((b << 11) + t0)) << 8) + o;
  bf16* pp = pooled + (((size_t)((b << 11) + t0)) << 8) + o;
#pragma unroll 4
  for (int tt = 0; tt < CLEN; ++tt) {
    __hip_bfloat162 uv = *(const __hip_bfloat162*)up; up += NU;
    float xv = b2f(*xp); xp += D_SPEC;
    float ur = b2f(uv.x) + xv, ui = b2f(uv.y);
    sr += c * ur - s * ui;
    si += c * ui + s * ur;
    float cn = c * cd - s * sd; s = s * cd + c * sd; c = cn;
    float r = norm * sr, im = norm * si;
    // |z| == new_mag exactly (phase never needed): mag2 = sqrt(new_mag^2 + eps)
    float he = sqrtf(r * r + im * im + 1e-8f);
    float nm = fmaxf(he - biaso, 0.f);
    float m2 = sqrtf(nm * nm + 1e-8f);
    m2 = row_reduce32(m2);                         // valid in lanes 31/63
    if (k == 31) *pp = __float2bfloat16(m2 * (1.f / 32.f));
    pp += D_SPEC;
  }
}

// ---------------------------------------------------------------------------
extern "C" void kernel_launch(void* const* d_in, const int* in_sizes, int n_in,
                              void* d_out, int out_size, void* d_ws, size_t ws_size,
                              hipStream_t stream) {
  const bf16* x        = (const bf16*)d_in[0];
  const bf16* conv_w   = (const bf16*)d_in[1];
  const bf16* mrb      = (const bf16*)d_in[2];
  const float* w_shared = (const float*)d_in[3];
  const float* b_shared = (const float*)d_in[4];
  const float* layer_w  = (const float*)d_in[5];
  const float* layer_b  = (const float*)d_in[6];
  float* out = (float*)d_out;

  char* ws = (char*)d_ws;
  bf16* Bmat   = (bf16*)(ws);                 // 16384*256*2   =   8,388,608 (dead after gemm<0>)
  float* totals = (float*)(ws);               // 4,194,304 — ALIASES Bmat (written by scan1 after gemm<0>)
  bf16* u      = (bf16*)(ws + 8388608);       // 4096*16384*2  = 134,217,728
  bf16* pooled = (bf16*)(ws + 143654912);     // 4096*256*2    =   2,097,152
  bf16* wsb    = (bf16*)(ws + 145752064);     // 768*256*2     =     393,216
  bf16* hidden = (bf16*)(ws + 146145280);     // 4096*768*2    =   6,291,456
  bf16* lwb    = (bf16*)(ws + 152436736);     // 4*1536*768*2  =   9,437,184  (end ~161.9 MB)

  prep<<<2048, 256, 0, stream>>>(conv_w, w_shared, layer_w, Bmat, wsb, lwb);

  // u[m][(o*32+k)*2+ri] = sum_i x[m][i] * conv_w[o,i,k,ri]
  gemm_k<0><<<dim3(NU / 128, MTOT / 128, 1), 256, 0, stream>>>(
      x, Bmat, u, nullptr, NU, D_SPEC, 0, 0, 0);

  scan1<<<BATCH * NCHUNK * 32, 256, 0, stream>>>(u, x, totals);
  tprefix<<<64, 256, 0, stream>>>(totals);
  scan2<<<BATCH * NCHUNK * 32, 256, 0, stream>>>(u, x, totals, mrb, pooled);

  // hidden = silu(pooled @ w_shared^T + b_shared)
  gemm_k<1><<<dim3(D_MODEL / 128, MTOT / 128, 1), 256, 0, stream>>>(
      pooled, wsb, hidden, b_shared, D_MODEL, D_SPEC, 0, 0, 0);

  // cond[l] = hidden @ layer_w[l]^T + layer_b[l]
  gemm_k<2><<<dim3(NCOND / 128, MTOT / 128, N_LAYERS), 256, 0, stream>>>(
      hidden, lwb, out, layer_b, NCOND, D_MODEL,
      (long long)MTOT * NCOND, (long long)NCOND * D_MODEL, NCOND);
}

// Round 4
// 357.315 us; speedup vs baseline: 1.4650x; 1.0670x over previous
//
#include <hip/hip_runtime.h>
#include <hip/hip_bf16.h>

typedef __hip_bfloat16 bf16;
typedef __attribute__((ext_vector_type(8))) short bf16x8;  // 8 bf16 in 4 VGPRs
typedef __attribute__((ext_vector_type(4))) float f32x4;

#define SEQ_LEN 2048
#define K_MAX   32
#define D_SPEC  256
#define D_MODEL 768
#define N_LAYERS 4
#define BATCH   2
#define MTOT    (BATCH * SEQ_LEN)       // 4096 rows (b*2048+t)
#define NU      (D_SPEC * K_MAX * 2)    // 16384 cols; n = (ok>>4)*32 + ri*16 + (ok&15)
#define NCOND   (2 * D_MODEL)           // 1536
#define NCHUNK  32
#define CLEN    64                      // SEQ_LEN / NCHUNK

__device__ inline float b2f(bf16 h) { return __bfloat162float(h); }

__device__ inline void gload16(const void* gp, void* lp) {
  __builtin_amdgcn_global_load_lds((const __attribute__((address_space(1))) void*)gp,
                                   (__attribute__((address_space(3))) void*)lp, 16, 0, 0);
}

// Full-rate DPP reduction over each 32-lane half; result valid in lanes 31 / 63.
__device__ inline float row_reduce32(float v) {
  v += __int_as_float(__builtin_amdgcn_update_dpp(0, __float_as_int(v), 0x111, 0xF, 0xF, true)); // row_shr:1
  v += __int_as_float(__builtin_amdgcn_update_dpp(0, __float_as_int(v), 0x112, 0xF, 0xF, true)); // row_shr:2
  v += __int_as_float(__builtin_amdgcn_update_dpp(0, __float_as_int(v), 0x114, 0xF, 0xF, true)); // row_shr:4
  v += __int_as_float(__builtin_amdgcn_update_dpp(0, __float_as_int(v), 0x118, 0xF, 0xF, true)); // row_shr:8
  v += __int_as_float(__builtin_amdgcn_update_dpp(0, __float_as_int(v), 0x142, 0xF, 0xF, true)); // row_bcast:15
  return v;
}

// ---------------------------------------------------------------------------
// prep: Bmat[n*256+i] = conv_w[o,i,k,ri] with interleaved n = (ok>>4)*32 + ri*16 + (ok&15),
//       ok = o*32+k. Re (ri=0) in even 16-col groups, im in odd groups, so a GEMM lane
//       holds the (re,im) pair of one chain in nt-pairs (0,1)/(2,3).
// ---------------------------------------------------------------------------
__global__ void prep(const bf16* __restrict__ conv_w, const float* __restrict__ w_shared,
                     const float* __restrict__ layer_w,
                     bf16* __restrict__ Bmat, bf16* __restrict__ wsb, bf16* __restrict__ lwb) {
  int idx = blockIdx.x * blockDim.x + threadIdx.x;
  int stride = gridDim.x * blockDim.x;
  for (int j = idx; j < NU * D_SPEC; j += stride) {
    int n = j >> 8, i = j & 255;
    int g = n >> 5, ri = (n >> 4) & 1, c = n & 15;
    int ok = (g << 4) + c, o = ok >> 5, k = ok & 31;
    Bmat[j] = conv_w[o * 16384 + i * 64 + k * 2 + ri];
  }
  for (int j = idx; j < D_MODEL * D_SPEC; j += stride) wsb[j] = __float2bfloat16(w_shared[j]);
  for (int j = idx; j < N_LAYERS * NCOND * D_MODEL; j += stride) lwb[j] = __float2bfloat16(layer_w[j]);
}

// ---------------------------------------------------------------------------
// u-GEMM with fused rotate/add-x/scale epilogue + chunk-total accumulation.
// Writes v[m][ok] = bf162( norm*tw(t,k)*(u+x) ), and totals[b][chunk][ok][2].
// ---------------------------------------------------------------------------
__global__ __launch_bounds__(256, 2) void gemm_v(
    const bf16* __restrict__ A, const bf16* __restrict__ B, const bf16* __restrict__ x,
    bf16* __restrict__ v, float* __restrict__ totals) {
  __shared__ bf16 As[128 * 32];
  __shared__ bf16 Bs[128 * 32];
  const int tid = threadIdx.x;
  const int wave = tid >> 6, lane = tid & 63;
  const int wm = (wave >> 1) << 6, wn = (wave & 1) << 6;
  const int lrow = lane & 15, quad = lane >> 4;
  const int m0 = blockIdx.y << 7, n0 = blockIdx.x << 7;
  const int K = D_SPEC;

  f32x4 acc[4][4] = {};

  for (int k0 = 0; k0 < K; k0 += 32) {
#pragma unroll
    for (int c = 0; c < 2; ++c) {
      int rr = ((wave * 2 + c) << 4) + (lane >> 2);
      int cb = (lane & 3) << 4;
      int lq = (((wave * 2 + c) << 6) + lane) << 4;
      gload16((const char*)A + (((size_t)(m0 + rr) * K + k0) << 1) + cb, (char*)As + lq);
      gload16((const char*)B + (((size_t)(n0 + rr) * K + k0) << 1) + cb, (char*)Bs + lq);
    }
    __syncthreads();
    bf16x8 af[4], bfr[4];
#pragma unroll
    for (int i = 0; i < 4; ++i) {
      af[i]  = *(const bf16x8*)(As + ((wm + (i << 4) + lrow) << 5) + (quad << 3));
      bfr[i] = *(const bf16x8*)(Bs + ((wn + (i << 4) + lrow) << 5) + (quad << 3));
    }
#pragma unroll
    for (int mt = 0; mt < 4; ++mt)
#pragma unroll
      for (int nt = 0; nt < 4; ++nt)
        acc[mt][nt] = __builtin_amdgcn_mfma_f32_16x16x32_bf16(af[mt], bfr[nt], acc[mt][nt], 0, 0, 0);
    __syncthreads();
  }

  // ---- fused epilogue ----
  const float c1 = -6.283185307179586f / 2048.0f;
  const float norm = 0.022097086912079608f;  // 1/sqrt(2048)
  const int mbase = m0 + wm;                 // 64-row slab == exactly one chunk
  const int b = mbase >> 11;
  const int chunk = (mbase >> 6) & 31;
  const int g0 = (n0 + wn) >> 5;

#pragma unroll
  for (int j = 0; j < 2; ++j) {
    const int ok = ((g0 + j) << 4) + lrow;
    const int k = ok & 31, o = ok >> 5;      // o is lane-uniform within the group
    float sumr = 0.f, sumi = 0.f;
#pragma unroll
    for (int mt = 0; mt < 4; ++mt) {
#pragma unroll
      for (int r = 0; r < 4; ++r) {
        int m = mbase + (mt << 4) + (quad << 2) + r;
        int t = m & 2047;
        float s, cv;
        __sincosf(c1 * (float)((t * k) & 2047), &s, &cv);
        float xv = b2f(x[((size_t)m << 8) + o]);
        float ur = acc[mt][2 * j][r] + xv;
        float ui = acc[mt][2 * j + 1][r];
        float vr = norm * (cv * ur - s * ui);
        float vi = norm * (cv * ui + s * ur);
        sumr += vr; sumi += vi;
        __hip_bfloat162 pk;
        pk.x = __float2bfloat16(vr);
        pk.y = __float2bfloat16(vi);
        *(__hip_bfloat162*)(v + ((((size_t)m << 13) + ok) << 1)) = pk;
      }
    }
    sumr += __shfl_xor(sumr, 16, 64); sumr += __shfl_xor(sumr, 32, 64);
    sumi += __shfl_xor(sumi, 16, 64); sumi += __shfl_xor(sumi, 32, 64);
    if (quad == 0) {
      size_t tb = ((((size_t)(b * NCHUNK + chunk)) << 13) + ok) << 1;
      totals[tb] = sumr; totals[tb + 1] = sumi;
    }
  }
}

// ---------------------------------------------------------------------------
// Plain GEMM for the two dense projections.
// EPI 1: +bias, SiLU, store bf16 ; EPI 2: +bias[z], store f32
// ---------------------------------------------------------------------------
template <int EPI>
__global__ __launch_bounds__(256, 2) void gemm_k(
    const bf16* __restrict__ A, const bf16* __restrict__ B, void* __restrict__ Cp,
    const float* __restrict__ bias, int N, int K,
    long long c_bstride, long long b_bstride, int bias_bstride) {
  __shared__ bf16 As[128 * 32];
  __shared__ bf16 Bs[128 * 32];
  const int tid = threadIdx.x;
  const int wave = tid >> 6, lane = tid & 63;
  const int wm = (wave >> 1) << 6, wn = (wave & 1) << 6;
  const int lrow = lane & 15, quad = lane >> 4;
  const int m0 = blockIdx.y << 7, n0 = blockIdx.x << 7;
  const int z = blockIdx.z;
  const bf16* Bz = B + (size_t)z * b_bstride;

  f32x4 acc[4][4] = {};

  for (int k0 = 0; k0 < K; k0 += 32) {
#pragma unroll
    for (int c = 0; c < 2; ++c) {
      int rr = ((wave * 2 + c) << 4) + (lane >> 2);
      int cb = (lane & 3) << 4;
      int lq = (((wave * 2 + c) << 6) + lane) << 4;
      gload16((const char*)A  + (((size_t)(m0 + rr) * K + k0) << 1) + cb, (char*)As + lq);
      gload16((const char*)Bz + (((size_t)(n0 + rr) * K + k0) << 1) + cb, (char*)Bs + lq);
    }
    __syncthreads();
    bf16x8 af[4], bfr[4];
#pragma unroll
    for (int i = 0; i < 4; ++i) {
      af[i]  = *(const bf16x8*)(As + ((wm + (i << 4) + lrow) << 5) + (quad << 3));
      bfr[i] = *(const bf16x8*)(Bs + ((wn + (i << 4) + lrow) << 5) + (quad << 3));
    }
#pragma unroll
    for (int mt = 0; mt < 4; ++mt)
#pragma unroll
      for (int nt = 0; nt < 4; ++nt)
        acc[mt][nt] = __builtin_amdgcn_mfma_f32_16x16x32_bf16(af[mt], bfr[nt], acc[mt][nt], 0, 0, 0);
    __syncthreads();
  }

#pragma unroll
  for (int mt = 0; mt < 4; ++mt) {
#pragma unroll
    for (int nt = 0; nt < 4; ++nt) {
#pragma unroll
      for (int r = 0; r < 4; ++r) {
        int gm = m0 + wm + (mt << 4) + (quad << 2) + r;
        int gn = n0 + wn + (nt << 4) + lrow;
        float v = acc[mt][nt][r];
        if (EPI == 1) {
          v += bias[gn];
          v = v / (1.f + __expf(-v));                    // SiLU
          ((bf16*)Cp)[(size_t)gm * N + gn] = __float2bfloat16(v);
        } else {
          v += bias[(size_t)z * bias_bstride + gn];
          ((float*)Cp)[(size_t)z * c_bstride + (size_t)gm * N + gn] = v;
        }
      }
    }
  }
}

// In-place exclusive prefix over chunks for each of the 16384 chains.
__global__ void tprefix(float* __restrict__ totals) {
  int id = blockIdx.x * blockDim.x + threadIdx.x;   // (b<<13) + ok
  int b = id >> 13, ok = id & 8191;
  float sr = 0.f, si = 0.f;
  for (int cc = 0; cc < NCHUNK; ++cc) {
    size_t idx = ((((size_t)(b * NCHUNK + cc)) << 13) + ok) << 1;
    float tr = totals[idx], ti = totals[idx + 1];
    totals[idx] = sr; totals[idx + 1] = si;
    sr += tr; si += ti;
  }
}

// ---------------------------------------------------------------------------
// Slim scan: v already rotated/normed/x-folded. Per step: complex add + magnitude
// + modReLU + DPP k-reduction.
// ---------------------------------------------------------------------------
__global__ __launch_bounds__(256) void scan2(const bf16* __restrict__ v,
                                             const float* __restrict__ totals,
                                             const bf16* __restrict__ mrb, bf16* __restrict__ pooled) {
  const int bId = blockIdx.x;
  const int ogrp = bId & 31, chunk = (bId >> 5) & 31, b = bId >> 10;
  const int tid = threadIdx.x, o_sub = tid >> 5, k = tid & 31;
  const int o = (ogrp << 3) + o_sub;
  const int ok = (o << 5) + k;
  const int t0 = chunk << 6;
  size_t tb = ((((size_t)(b * NCHUNK + chunk)) << 13) + ok) << 1;
  float sr = totals[tb], si = totals[tb + 1];
  const float biaso = b2f(mrb[o]);
  const bf16* vp = v + (((((size_t)((b << 11) + t0)) << 13) + ok) << 1);
  bf16* pp = pooled + (((size_t)((b << 11) + t0)) << 8) + o;
#pragma unroll 8
  for (int tt = 0; tt < CLEN; ++tt) {
    __hip_bfloat162 uv = *(const __hip_bfloat162*)vp; vp += (size_t)NU;
    sr += b2f(uv.x); si += b2f(uv.y);
    float he = __builtin_amdgcn_sqrtf(sr * sr + si * si + 1e-8f);
    float nm = fmaxf(he - biaso, 0.f);   // == |z| == mag2 up to +1e-4 at nm=0
    float m2 = row_reduce32(nm);         // valid in lanes 31/63
    if (k == 31) *pp = __float2bfloat16(m2 * (1.f / 32.f));
    pp += D_SPEC;
  }
}

// ---------------------------------------------------------------------------
extern "C" void kernel_launch(void* const* d_in, const int* in_sizes, int n_in,
                              void* d_out, int out_size, void* d_ws, size_t ws_size,
                              hipStream_t stream) {
  const bf16* x        = (const bf16*)d_in[0];
  const bf16* conv_w   = (const bf16*)d_in[1];
  const bf16* mrb      = (const bf16*)d_in[2];
  const float* w_shared = (const float*)d_in[3];
  const float* b_shared = (const float*)d_in[4];
  const float* layer_w  = (const float*)d_in[5];
  const float* layer_b  = (const float*)d_in[6];
  float* out = (float*)d_out;

  char* ws = (char*)d_ws;
  bf16* Bmat   = (bf16*)(ws);                 // 16384*256*2   =   8,388,608
  bf16* v      = (bf16*)(ws + 8388608);       // 4096*16384*2  = 134,217,728
  bf16* pooled = (bf16*)(ws + 143654912);     // 4096*256*2    =   2,097,152
  bf16* wsb    = (bf16*)(ws + 145752064);     // 768*256*2     =     393,216
  bf16* hidden = (bf16*)(ws + 146145280);     // 4096*768*2    =   6,291,456
  float* totals = (float*)(ws + 146145280);   // 4 MB — ALIASES hidden (totals dead before gemm<1> writes)
  bf16* lwb    = (bf16*)(ws + 152436736);     // 4*1536*768*2  =   9,437,184  (end ~161.9 MB)

  prep<<<2048, 256, 0, stream>>>(conv_w, w_shared, layer_w, Bmat, wsb, lwb);

  // v = norm*tw*(x@convW + x_self), plus per-chunk totals (scan1 fused away)
  gemm_v<<<dim3(NU / 128, MTOT / 128, 1), 256, 0, stream>>>(x, Bmat, x, v, totals);

  tprefix<<<64, 256, 0, stream>>>(totals);
  scan2<<<BATCH * NCHUNK * 32, 256, 0, stream>>>(v, totals, mrb, pooled);

  // hidden = silu(pooled @ w_shared^T + b_shared)
  gemm_k<1><<<dim3(D_MODEL / 128, MTOT / 128, 1), 256, 0, stream>>>(
      pooled, wsb, hidden, b_shared, D_MODEL, D_SPEC, 0, 0, 0);

  // cond[l] = hidden @ layer_w[l]^T + layer_b[l]
  gemm_k<2><<<dim3(NCOND / 128, MTOT / 128, N_LAYERS), 256, 0, stream>>>(
      hidden, lwb, out, layer_b, NCOND, D_MODEL,
      (long long)MTOT * NCOND, (long long)NCOND * D_MODEL, NCOND);
}

// Round 5
// 333.564 us; speedup vs baseline: 1.5693x; 1.0712x over previous
//
#include <hip/hip_runtime.h>
#include <hip/hip_bf16.h>

typedef __hip_bfloat16 bf16;
typedef __attribute__((ext_vector_type(8))) short bf16x8;  // 8 bf16 in 4 VGPRs
typedef __attribute__((ext_vector_type(4))) float f32x4;

#define SEQ_LEN 2048
#define K_MAX   32
#define D_SPEC  256
#define D_MODEL 768
#define N_LAYERS 4
#define BATCH   2
#define MTOT    (BATCH * SEQ_LEN)       // 4096 rows (b*2048+t)
#define NU      (D_SPEC * K_MAX * 2)    // 16384 cols; n = (ok>>4)*32 + ri*16 + (ok&15)
#define NCOND   (2 * D_MODEL)           // 1536
#define NCHUNK  32
#define CLEN    64                      // SEQ_LEN / NCHUNK

__device__ inline float b2f(bf16 h) { return __bfloat162float(h); }

__device__ inline void gload16(const void* gp, void* lp) {
  __builtin_amdgcn_global_load_lds((const __attribute__((address_space(1))) void*)gp,
                                   (__attribute__((address_space(3))) void*)lp, 16, 0, 0);
}

// LDS XOR swizzle: granule (row R, 16B-col q) lives at granule slot R*4 + (q ^ (R&3) ^ ((R>>2)&3)).
// Staging lane L (slot D = wavebase+L) therefore fetches global col c16 = (L&3)^((L>>2)&3)^((L>>4)&3)
// of row D>>2 — a permutation within each 64B row, so global coalescing is unchanged.
__device__ inline int stage_c16(int lane) { return ((lane & 3) ^ ((lane >> 2) & 3) ^ ((lane >> 4) & 3)); }
__device__ inline int frag_off(int R, int q) {        // bf16-element offset of fragment (R, q)
  return (R << 5) + (((q ^ (R & 3) ^ ((R >> 2) & 3)) & 3) << 3);
}

// ---------------------------------------------------------------------------
// prep: Bmat (B^T, interleaved re/im groups), bf16 casts of w_shared/layer_w,
//       and the twiddle table twtab[t*32+k] = (cos, sin) in f32.
// ---------------------------------------------------------------------------
__global__ void prep(const bf16* __restrict__ conv_w, const float* __restrict__ w_shared,
                     const float* __restrict__ layer_w,
                     bf16* __restrict__ Bmat, bf16* __restrict__ wsb, bf16* __restrict__ lwb,
                     float2* __restrict__ twtab) {
  int idx = blockIdx.x * blockDim.x + threadIdx.x;
  int stride = gridDim.x * blockDim.x;
  for (int j = idx; j < NU * D_SPEC; j += stride) {
    int n = j >> 8, i = j & 255;
    int g = n >> 5, ri = (n >> 4) & 1, c = n & 15;
    int ok = (g << 4) + c, o = ok >> 5, k = ok & 31;
    Bmat[j] = conv_w[o * 16384 + i * 64 + k * 2 + ri];
  }
  for (int j = idx; j < D_MODEL * D_SPEC; j += stride) wsb[j] = __float2bfloat16(w_shared[j]);
  for (int j = idx; j < N_LAYERS * NCOND * D_MODEL; j += stride) lwb[j] = __float2bfloat16(layer_w[j]);
  for (int j = idx; j < SEQ_LEN * K_MAX; j += stride) {
    int t = j >> 5, k = j & 31;
    float ang = (-6.283185307179586f / 2048.0f) * (float)((t * k) & 2047);
    float s, c; sincosf(ang, &s, &c);
    twtab[j] = make_float2(c, s);
  }
}

// ---------------------------------------------------------------------------
// u-GEMM + fused epilogue: rotate (table), fold x, scale, INTRA-CHUNK PREFIX
// (register scan + cross-quad shuffle scan), store prefixed v + chunk totals.
// ---------------------------------------------------------------------------
__global__ __launch_bounds__(256, 3) void gemm_v(
    const bf16* __restrict__ A, const bf16* __restrict__ B, const bf16* __restrict__ x,
    const float2* __restrict__ twtab, bf16* __restrict__ v, float* __restrict__ totals) {
  __shared__ bf16 As[128 * 32];
  __shared__ bf16 Bs[128 * 32];
  const int tid = threadIdx.x;
  const int wave = tid >> 6, lane = tid & 63;
  const int wm = (wave >> 1) << 6, wn = (wave & 1) << 6;
  const int lrow = lane & 15, quad = lane >> 4;
  const int m0 = blockIdx.y << 7, n0 = blockIdx.x << 7;
  const int K = D_SPEC;

  f32x4 acc[4][4] = {};

  for (int k0 = 0; k0 < K; k0 += 32) {
#pragma unroll
    for (int c = 0; c < 2; ++c) {
      int rr = ((wave * 2 + c) << 4) + (lane >> 2);
      int cb = stage_c16(lane) << 4;
      int lq = (((wave * 2 + c) << 6) + lane) << 4;
      gload16((const char*)A + (((size_t)(m0 + rr) * K + k0) << 1) + cb, (char*)As + lq);
      gload16((const char*)B + (((size_t)(n0 + rr) * K + k0) << 1) + cb, (char*)Bs + lq);
    }
    __syncthreads();
    bf16x8 af[4], bfr[4];
#pragma unroll
    for (int i = 0; i < 4; ++i) {
      af[i]  = *(const bf16x8*)(As + frag_off(wm + (i << 4) + lrow, quad));
      bfr[i] = *(const bf16x8*)(Bs + frag_off(wn + (i << 4) + lrow, quad));
    }
#pragma unroll
    for (int mt = 0; mt < 4; ++mt)
#pragma unroll
      for (int nt = 0; nt < 4; ++nt)
        acc[mt][nt] = __builtin_amdgcn_mfma_f32_16x16x32_bf16(af[mt], bfr[nt], acc[mt][nt], 0, 0, 0);
    __syncthreads();
  }

  // ---- fused epilogue: rotate + prefix + store ----
  const float norm = 0.022097086912079608f;  // 1/sqrt(2048)
  const int mbase = m0 + wm;                 // 64-row slab == exactly one chunk
  const int b = mbase >> 11;
  const int chunk = (mbase >> 6) & 31;
  const int g0 = (n0 + wn) >> 5;             // always even
  const int o = g0 >> 1;                     // lane-uniform; same for j=0,1

  // fold x into the two re-planes once
#pragma unroll
  for (int mt = 0; mt < 4; ++mt)
#pragma unroll
    for (int r = 0; r < 4; ++r) {
      int m = mbase + (mt << 4) + (quad << 2) + r;
      float xv = b2f(x[((size_t)m << 8) + o]);
      acc[mt][0][r] += xv;
      acc[mt][2][r] += xv;
    }

#pragma unroll
  for (int j = 0; j < 2; ++j) {
    const int k = lrow + (j << 4);
    const int ok = ((g0 + j) << 4) + lrow;
    float carry_r = 0.f, carry_i = 0.f;
#pragma unroll
    for (int mt = 0; mt < 4; ++mt) {
      float vr[4], vi[4];
#pragma unroll
      for (int r = 0; r < 4; ++r) {
        int t = (mbase + (mt << 4) + (quad << 2) + r) & 2047;
        float2 tw = twtab[(t << 5) + k];
        float ur = acc[mt][2 * j][r], ui = acc[mt][2 * j + 1][r];
        vr[r] = norm * (tw.x * ur - tw.y * ui);
        vi[r] = norm * (tw.x * ui + tw.y * ur);
      }
      // sequential inclusive prefix over r
      vr[1] += vr[0]; vr[2] += vr[1]; vr[3] += vr[2];
      vi[1] += vi[0]; vi[2] += vi[1]; vi[3] += vi[2];
      float Qr = vr[3], Qi = vi[3];          // own-quad total
      float Tr = Qr, Ti = Qi;                // inclusive scan over quads (same lrow column)
      float tr = __shfl(Tr, lane - 16, 64), ti = __shfl(Ti, lane - 16, 64);
      if (quad >= 1) { Tr += tr; Ti += ti; }
      tr = __shfl(Tr, lane - 32, 64); ti = __shfl(Ti, lane - 32, 64);
      if (quad >= 2) { Tr += tr; Ti += ti; }
      float Er = Tr - Qr + carry_r, Ei = Ti - Qi + carry_i;  // exclusive base
      float c3r = __shfl(Tr, 48 + lrow, 64), c3i = __shfl(Ti, 48 + lrow, 64);  // 16-t block total
      carry_r += c3r; carry_i += c3i;
#pragma unroll
      for (int r = 0; r < 4; ++r) {
        int m = mbase + (mt << 4) + (quad << 2) + r;
        __hip_bfloat162 pk;
        pk.x = __float2bfloat16(vr[r] + Er);
        pk.y = __float2bfloat16(vi[r] + Ei);
        *(__hip_bfloat162*)(v + ((((size_t)m << 13) + ok) << 1)) = pk;
      }
    }
    if (quad == 0) {                          // carry == chunk total
      size_t tb = ((((size_t)(b * NCHUNK + chunk)) << 13) + ok) << 1;
      totals[tb] = carry_r; totals[tb + 1] = carry_i;
    }
  }
}

// ---------------------------------------------------------------------------
// Plain GEMM for the two dense projections (swizzled LDS).
// EPI 1: +bias, SiLU, store bf16 ; EPI 2: +bias[z], store f32
// ---------------------------------------------------------------------------
template <int EPI>
__global__ __launch_bounds__(256, 2) void gemm_k(
    const bf16* __restrict__ A, const bf16* __restrict__ B, void* __restrict__ Cp,
    const float* __restrict__ bias, int N, int K,
    long long c_bstride, long long b_bstride, int bias_bstride) {
  __shared__ bf16 As[128 * 32];
  __shared__ bf16 Bs[128 * 32];
  const int tid = threadIdx.x;
  const int wave = tid >> 6, lane = tid & 63;
  const int wm = (wave >> 1) << 6, wn = (wave & 1) << 6;
  const int lrow = lane & 15, quad = lane >> 4;
  const int m0 = blockIdx.y << 7, n0 = blockIdx.x << 7;
  const int z = blockIdx.z;
  const bf16* Bz = B + (size_t)z * b_bstride;

  f32x4 acc[4][4] = {};

  for (int k0 = 0; k0 < K; k0 += 32) {
#pragma unroll
    for (int c = 0; c < 2; ++c) {
      int rr = ((wave * 2 + c) << 4) + (lane >> 2);
      int cb = stage_c16(lane) << 4;
      int lq = (((wave * 2 + c) << 6) + lane) << 4;
      gload16((const char*)A  + (((size_t)(m0 + rr) * K + k0) << 1) + cb, (char*)As + lq);
      gload16((const char*)Bz + (((size_t)(n0 + rr) * K + k0) << 1) + cb, (char*)Bs + lq);
    }
    __syncthreads();
    bf16x8 af[4], bfr[4];
#pragma unroll
    for (int i = 0; i < 4; ++i) {
      af[i]  = *(const bf16x8*)(As + frag_off(wm + (i << 4) + lrow, quad));
      bfr[i] = *(const bf16x8*)(Bs + frag_off(wn + (i << 4) + lrow, quad));
    }
#pragma unroll
    for (int mt = 0; mt < 4; ++mt)
#pragma unroll
      for (int nt = 0; nt < 4; ++nt)
        acc[mt][nt] = __builtin_amdgcn_mfma_f32_16x16x32_bf16(af[mt], bfr[nt], acc[mt][nt], 0, 0, 0);
    __syncthreads();
  }

#pragma unroll
  for (int mt = 0; mt < 4; ++mt) {
#pragma unroll
    for (int nt = 0; nt < 4; ++nt) {
#pragma unroll
      for (int r = 0; r < 4; ++r) {
        int gm = m0 + wm + (mt << 4) + (quad << 2) + r;
        int gn = n0 + wn + (nt << 4) + lrow;
        float v = acc[mt][nt][r];
        if (EPI == 1) {
          v += bias[gn];
          v = v / (1.f + __expf(-v));                    // SiLU
          ((bf16*)Cp)[(size_t)gm * N + gn] = __float2bfloat16(v);
        } else {
          v += bias[(size_t)z * bias_bstride + gn];
          ((float*)Cp)[(size_t)z * c_bstride + (size_t)gm * N + gn] = v;
        }
      }
    }
  }
}

// In-place exclusive prefix over chunks for each of the 16384 chains.
__global__ void tprefix(float* __restrict__ totals) {
  int id = blockIdx.x * blockDim.x + threadIdx.x;   // (b<<13) + ok
  int b = id >> 13, ok = id & 8191;
  float sr = 0.f, si = 0.f;
  for (int cc = 0; cc < NCHUNK; ++cc) {
    size_t idx = ((((size_t)(b * NCHUNK + cc)) << 13) + ok) << 1;
    float tr = totals[idx], ti = totals[idx + 1];
    totals[idx] = sr; totals[idx + 1] = si;
    sr += tr; si += ti;
  }
}

// ---------------------------------------------------------------------------
// pool: v holds intra-chunk PREFIXED values; add chunk carry-in, modReLU
// magnitude, mean over k. Fully parallel, coalesced dwordx4 loads.
// Thread layout: id -> m = id>>11, o = (id&2047)>>3, kg = id&7 (4 chains each).
// ---------------------------------------------------------------------------
__global__ __launch_bounds__(256) void pool(const bf16* __restrict__ v,
                                            const float* __restrict__ totals,
                                            const bf16* __restrict__ mrb, bf16* __restrict__ pooled) {
  int id = blockIdx.x * 256 + threadIdx.x;
  int m = id >> 11, rem = id & 2047;
  int o = rem >> 3, kg = rem & 7;
  int ok0 = (o << 5) + (kg << 2);
  int b = m >> 11, chunk = (m >> 6) & 31;

  const uint4 raw = *(const uint4*)((const char*)v + ((((size_t)m << 13) + ok0) << 2));
  size_t tb = ((((size_t)(b * NCHUNK + chunk)) << 13) + ok0) << 1;
  const f32x4 car1 = *(const f32x4*)(totals + tb);
  const f32x4 car2 = *(const f32x4*)(totals + tb + 4);
  const float biaso = b2f(mrb[o]);

  unsigned w[4] = {raw.x, raw.y, raw.z, raw.w};
  float cr[4] = {car1.x, car1.z, car2.x, car2.z};
  float ci[4] = {car1.y, car1.w, car2.y, car2.w};
  float acc = 0.f;
#pragma unroll
  for (int c = 0; c < 4; ++c) {
    float vr = __uint_as_float(w[c] << 16);
    float vi = __uint_as_float(w[c] & 0xffff0000u);
    float sr = vr + cr[c], si = vi + ci[c];
    float he = __builtin_amdgcn_sqrtf(sr * sr + si * si + 1e-8f);
    acc += fmaxf(he - biaso, 0.f);
  }
  acc += __shfl_xor(acc, 1, 64);
  acc += __shfl_xor(acc, 2, 64);
  acc += __shfl_xor(acc, 4, 64);
  if (kg == 0) pooled[((size_t)m << 8) + o] = __float2bfloat16(acc * (1.f / 32.f));
}

// ---------------------------------------------------------------------------
extern "C" void kernel_launch(void* const* d_in, const int* in_sizes, int n_in,
                              void* d_out, int out_size, void* d_ws, size_t ws_size,
                              hipStream_t stream) {
  const bf16* x        = (const bf16*)d_in[0];
  const bf16* conv_w   = (const bf16*)d_in[1];
  const bf16* mrb      = (const bf16*)d_in[2];
  const float* w_shared = (const float*)d_in[3];
  const float* b_shared = (const float*)d_in[4];
  const float* layer_w  = (const float*)d_in[5];
  const float* layer_b  = (const float*)d_in[6];
  float* out = (float*)d_out;

  char* ws = (char*)d_ws;
  bf16* Bmat    = (bf16*)(ws);                 // 16384*256*2   =   8,388,608
  bf16* v       = (bf16*)(ws + 8388608);       // 4096*16384*2  = 134,217,728 (ends 142,606,336)
  float2* twtab = (float2*)(ws + 142606336);   // 2048*32*8     =     524,288
  bf16* pooled  = (bf16*)(ws + 143654912);     // 4096*256*2    =   2,097,152
  bf16* wsb     = (bf16*)(ws + 145752064);     // 768*256*2     =     393,216
  bf16* hidden  = (bf16*)(ws + 146145280);     // 4096*768*2    =   6,291,456
  float* totals = (float*)(ws + 146145280);    // 4 MB — ALIASES hidden (totals dead before gemm<1> writes)
  bf16* lwb     = (bf16*)(ws + 152436736);     // 4*1536*768*2  =   9,437,184  (end ~161.9 MB)

  prep<<<2048, 256, 0, stream>>>(conv_w, w_shared, layer_w, Bmat, wsb, lwb, twtab);

  // v = prefixed( norm*tw*(x@convW + x_self) ), totals = per-chunk complex sums
  gemm_v<<<dim3(NU / 128, MTOT / 128, 1), 256, 0, stream>>>(x, Bmat, x, twtab, v, totals);

  tprefix<<<64, 256, 0, stream>>>(totals);
  pool<<<(MTOT * 2048) / 256, 256, 0, stream>>>(v, totals, mrb, pooled);

  // hidden = silu(pooled @ w_shared^T + b_shared)
  gemm_k<1><<<dim3(D_MODEL / 128, MTOT / 128, 1), 256, 0, stream>>>(
      pooled, wsb, hidden, b_shared, D_MODEL, D_SPEC, 0, 0, 0);

  // cond[l] = hidden @ layer_w[l]^T + layer_b[l]
  gemm_k<2><<<dim3(NCOND / 128, MTOT / 128, N_LAYERS), 256, 0, stream>>>(
      hidden, lwb, out, layer_b, NCOND, D_MODEL,
      (long long)MTOT * NCOND, (long long)NCOND * D_MODEL, NCOND);
}